// Round 1
// baseline (381.120 us; speedup 1.0000x reference)
//
#include <hip/hip_runtime.h>

// RSCA fused kernel: AdaptiveAvgPool(7x7) + 4x scalar-embed MHA over B axis + residuals.
// B=128 (sequence axis attention mixes), N=8192 independent columns, x:[B,N,7,7] f32.
//
// Per column n, with q/k/v scalar affine transforms:
//   out_attn = wo*(wv*X̄ + bv) + bo, X̄ = softmax(q_i * k_j)-weighted mean of RAW kv values
// (uses sum_j a_ij == 1 so v's affine folds into the epilogue).
// LDS holds per kv-set float2 {Kl = (wk*raw+bk)*log2e, raw}; inner loop per attention is
// 1 fma (arg) + 1 v_exp_f32 + 1 fma (S1) + 1 add (S0) — minimal.

constexpr int B_SEQ = 128;   // attention/sequence axis
constexpr int N_COL = 8192;  // independent columns
constexpr int HWP   = 49;    // 7*7 pool window
constexpr int TC    = 8;     // columns per block
constexpr int RG    = 16;    // x rows staged per group
constexpr int NT    = 256;   // threads per block

__global__ __launch_bounds__(NT, 3) void rsca_fused(
    const float* __restrict__ x, const float* __restrict__ y,
    const float* __restrict__ pwq, const float* __restrict__ pwk,
    const float* __restrict__ pwv, const float* __restrict__ pbq,
    const float* __restrict__ pbk, const float* __restrict__ pbv,
    const float* __restrict__ pwo, const float* __restrict__ pbo,
    float* __restrict__ out)
{
    __shared__ float2 kvx[B_SEQ][TC];           // {Kl, raw} for x-derived kv set (pooled)
    __shared__ float2 kvy[B_SEQ][TC];           // {Kl, raw} for y-derived kv set
    __shared__ float  xstage[RG * TC * HWP];    // 16*392 floats = 25 KB staging
    __shared__ float  klmn[2][TC], klmx[2][TC]; // [0]=x-set, [1]=y-set per-column min/max of Kl

    const int t  = threadIdx.x;
    const int n0 = blockIdx.x * TC;

    const float wq = pwq[0], wk = pwk[0], wv = pwv[0];
    const float bq = pbq[0], bk = pbk[0], bv = pbv[0];
    const float wo = pwo[0], bo = pbo[0];
    const float L2E = 1.4426950408889634f;
    const float wkL = wk * L2E, bkL = bk * L2E;      // k transform with log2e folded in
    const float alpha = wo * wv;
    const float beta2 = 2.0f * (wo * bv + bo);

    // ---- stage y tile: kvy[b][c] ----
    for (int cell = t; cell < B_SEQ * TC; cell += NT) {
        const int b = cell >> 3, c = cell & 7;
        const float yv = y[b * N_COL + n0 + c];
        kvy[b][c] = make_float2(fmaf(yv, wkL, bkL), yv);
    }

    // ---- pool x into kvx: 8 groups of RG rows, LDS-staged coalesced float4 loads ----
    constexpr int ROWF4 = TC * HWP / 4;              // 98 float4 per row of the tile
    for (int g = 0; g < B_SEQ / RG; ++g) {
        __syncthreads();                             // protect xstage reuse (and y-stage on g=0)
        const int b0 = g * RG;
        for (int idx4 = t; idx4 < RG * ROWF4; idx4 += NT) {
            const int bl = idx4 / ROWF4;
            const int r4 = idx4 - bl * ROWF4;
            const float4* src = (const float4*)(x + ((size_t)(b0 + bl) * N_COL + n0) * HWP);
            ((float4*)xstage)[idx4] = src[r4];       // row start is 16B aligned (n0 % 8 == 0)
        }
        __syncthreads();
        if (t < RG * TC) {                           // 128 cells: each thread sums one (b,c)
            const int bl = t >> 3, c = t & 7;
            const float* p = xstage + (bl * TC + c) * HWP;  // stride-49 (odd): 2-way banks, free
            float s = 0.0f;
            #pragma unroll
            for (int k = 0; k < HWP; ++k) s += p[k];
            const float mean = s * (1.0f / HWP);
            kvx[b0 + bl][c] = make_float2(fmaf(mean, wkL, bkL), mean);
        }
    }
    __syncthreads();

    // ---- per-column min/max of Kl for both sets (softmax max via sign of q) ----
    if (t < 2 * TC) {
        const int c = t & 7, which = t >> 3;
        float mn = 3.4e38f, mx = -3.4e38f;
        for (int j = 0; j < B_SEQ; ++j) {
            const float v = which ? kvy[j][c].x : kvx[j][c].x;
            mn = fminf(mn, v);
            mx = fmaxf(mx, v);
        }
        klmn[which][c] = mn;
        klmx[which][c] = mx;
    }
    __syncthreads();

    // ---- attention: thread = (query i, column half); 4 columns each ----
    const int i  = t & (B_SEQ - 1);
    const int ch = t >> 7;                           // 0 or 1
    #pragma unroll
    for (int cc = 0; cc < TC / 2; ++cc) {
        const int c = ch + 2 * cc;                   // uniform within a wave -> LDS broadcast
        const float xi = kvx[i][c].y;
        const float yi = kvy[i][c].y;
        const float qx = fmaf(xi, wq, bq);
        const float qy = fmaf(yi, wq, bq);
        // softmax maxes: m = max_j q*Kl_j = q>=0 ? q*maxKl : q*minKl
        const float msx = qx >= 0.0f ? qx * klmx[0][c] : qx * klmn[0][c]; // self_x : qx vs kv-x
        const float mcy = qy >= 0.0f ? qy * klmx[0][c] : qy * klmn[0][c]; // cross_y: qy vs kv-x
        const float msy = qy >= 0.0f ? qy * klmx[1][c] : qy * klmn[1][c]; // self_y : qy vs kv-y
        const float mcx = qx >= 0.0f ? qx * klmx[1][c] : qx * klmn[1][c]; // cross_x: qx vs kv-y

        float s0sx = 0.f, s1sx = 0.f, s0cy = 0.f, s1cy = 0.f;
        float s0sy = 0.f, s1sy = 0.f, s0cx = 0.f, s1cx = 0.f;
        #pragma unroll 4
        for (int j = 0; j < B_SEQ; ++j) {
            const float2 kx = kvx[j][c];             // broadcast ds_read_b64
            const float2 ky = kvy[j][c];
            const float e1 = __builtin_amdgcn_exp2f(fmaf(qx, kx.x, -msx));
            const float e2 = __builtin_amdgcn_exp2f(fmaf(qy, kx.x, -mcy));
            const float e3 = __builtin_amdgcn_exp2f(fmaf(qy, ky.x, -msy));
            const float e4 = __builtin_amdgcn_exp2f(fmaf(qx, ky.x, -mcx));
            s1sx = fmaf(e1, kx.y, s1sx); s0sx += e1;
            s1cy = fmaf(e2, kx.y, s1cy); s0cy += e2;
            s1sy = fmaf(e3, ky.y, s1sy); s0sy += e3;
            s1cx = fmaf(e4, ky.y, s1cx); s0cx += e4;
        }
        const float mx_sx = s1sx * __builtin_amdgcn_rcpf(s0sx);
        const float mx_cx = s1cx * __builtin_amdgcn_rcpf(s0cx);
        const float my_sy = s1sy * __builtin_amdgcn_rcpf(s0sy);
        const float my_cy = s1cy * __builtin_amdgcn_rcpf(s0cy);
        const float outx = fmaf(alpha, mx_sx + mx_cx, beta2 + xi);
        const float outy = fmaf(alpha, my_sy + my_cy, beta2 + yi);
        out[(size_t)i * (2 * N_COL) + n0 + c]         = outx;
        out[(size_t)i * (2 * N_COL) + N_COL + n0 + c] = outy;
    }
}

extern "C" void kernel_launch(void* const* d_in, const int* in_sizes, int n_in,
                              void* d_out, int out_size, void* d_ws, size_t ws_size,
                              hipStream_t stream) {
    const float* x   = (const float*)d_in[0];
    const float* y   = (const float*)d_in[1];
    const float* pwq = (const float*)d_in[2];
    const float* pwk = (const float*)d_in[3];
    const float* pwv = (const float*)d_in[4];
    const float* pbq = (const float*)d_in[5];
    const float* pbk = (const float*)d_in[6];
    const float* pbv = (const float*)d_in[7];
    const float* pwo = (const float*)d_in[8];
    const float* pbo = (const float*)d_in[9];
    float* out = (float*)d_out;

    rsca_fused<<<dim3(N_COL / TC), dim3(NT), 0, stream>>>(
        x, y, pwq, pwk, pwv, pbq, pbk, pbv, pwo, pbo, out);
}

// Round 2
// 377.508 us; speedup vs baseline: 1.0096x; 1.0096x over previous
//
#include <hip/hip_runtime.h>

// RSCA split: (1) pool x[128,8192,7,7] -> xp[128,8192] in d_ws (memory-bound),
// (2) 4x scalar-embed MHA over B=128 axis + residuals (VALU/exp-bound).
//
// Attention math per column n: out_attn = wo*(wv*X̄+bv)+bo where X̄ is the
// softmax(q_i*k_j)-weighted mean of RAW kv values (Σa=1 folds v's affine out).
// k stored pre-scaled by log2e -> inner loop = fma + v_exp2 + fma + add per attn.

constexpr int B_SEQ = 128;
constexpr int N_COL = 8192;
constexpr int HWP   = 49;
constexpr int NT    = 256;
constexpr int TC    = 4;     // columns per attention block
constexpr int PC    = 128;   // cells per pool tile

// ---------------- kernel 1: adaptive avg pool ----------------
__global__ __launch_bounds__(NT) void rsca_pool(
    const float* __restrict__ x, float* __restrict__ xp)
{
    __shared__ float st[PC * HWP];                 // 25088 B -> 6 blocks/CU
    const int t = threadIdx.x;
    const int ntiles = (B_SEQ * N_COL) / PC;       // 8192
    for (int tile = blockIdx.x; tile < ntiles; tile += gridDim.x) {
        const size_t cell0 = (size_t)tile * PC;
        const float4* src = (const float4*)(x + cell0 * HWP);  // 25088B-aligned
        __syncthreads();                           // protect st reuse
        for (int k = t; k < PC * HWP / 4; k += NT)
            ((float4*)st)[k] = src[k];             // fully coalesced
        __syncthreads();
        // 2 threads per cell, branch-free split 25/24, combine via shfl_xor
        const int cell = t >> 1, half = t & 1;
        const float* p = st + cell * HWP + half * 25;
        float s = 0.0f;
        #pragma unroll
        for (int k = 0; k < 24; ++k) s += p[k];
        if (half == 0) s += p[24];
        s += __shfl_xor(s, 1);
        if (half == 0) xp[cell0 + cell] = s * (1.0f / HWP);
    }
}

// ---------------- kernel 2: quad attention + residuals ----------------
__global__ __launch_bounds__(NT, 6) void rsca_attn(
    const float* __restrict__ xp, const float* __restrict__ y,
    const float* __restrict__ pwq, const float* __restrict__ pwk,
    const float* __restrict__ pwv, const float* __restrict__ pbq,
    const float* __restrict__ pbk, const float* __restrict__ pbv,
    const float* __restrict__ pwo, const float* __restrict__ pbo,
    float* __restrict__ out)
{
    __shared__ float2 kvxT[TC][B_SEQ];             // [c][j] {Kl, raw}, j contiguous
    __shared__ float2 kvyT[TC][B_SEQ];
    __shared__ float  pmn[2][TC][8], pmx[2][TC][8];
    __shared__ float  klmn[2][TC], klmx[2][TC];

    const int t  = threadIdx.x;
    const int n0 = blockIdx.x * TC;

    const float wq = pwq[0], wk = pwk[0], wv = pwv[0];
    const float bq = pbq[0], bk = pbk[0], bv = pbv[0];
    const float wo = pwo[0], bo = pbo[0];
    const float L2E = 1.4426950408889634f;
    const float wkL = wk * L2E, bkL = bk * L2E;
    const float alpha = wo * wv;
    const float beta2 = 2.0f * (wo * bv + bo);

    // stage kv tiles (512 cells per set)
    for (int cell = t; cell < B_SEQ * TC; cell += NT) {
        const int j = cell >> 2, c = cell & 3;
        const float fx = xp[(size_t)j * N_COL + n0 + c];
        const float fy = y [(size_t)j * N_COL + n0 + c];
        kvxT[c][j] = make_float2(fmaf(fx, wkL, bkL), fx);
        kvyT[c][j] = make_float2(fmaf(fy, wkL, bkL), fy);
    }
    __syncthreads();

    // per-(set,c) min/max of Kl: 64 threads produce 8 partials each task
    if (t < 64) {
        const int set = t >> 5, c = (t >> 3) & 3, part = t & 7;
        float mn = 3.4e38f, mx = -3.4e38f;
        #pragma unroll
        for (int k = 0; k < 16; ++k) {
            const int j = part * 16 + k;
            const float v = set ? kvyT[c][j].x : kvxT[c][j].x;
            mn = fminf(mn, v);
            mx = fmaxf(mx, v);
        }
        pmn[set][c][part] = mn;
        pmx[set][c][part] = mx;
    }
    __syncthreads();
    if (t < 8) {
        const int set = t >> 2, c = t & 3;
        float mn = 3.4e38f, mx = -3.4e38f;
        #pragma unroll
        for (int k = 0; k < 8; ++k) {
            mn = fminf(mn, pmn[set][c][k]);
            mx = fmaxf(mx, pmx[set][c][k]);
        }
        klmn[set][c] = mn;
        klmx[set][c] = mx;
    }
    __syncthreads();

    // attention: thread = (query i, half ch); 2 columns each, wave-uniform c
    const int i  = t & (B_SEQ - 1);
    const int ch = t >> 7;
    #pragma unroll
    for (int cc = 0; cc < 2; ++cc) {
        const int c = ch * 2 + cc;
        const float2* __restrict__ px = kvxT[c];
        const float2* __restrict__ py = kvyT[c];
        const float xi = px[i].y;
        const float yi = py[i].y;
        const float qx = fmaf(xi, wq, bq);
        const float qy = fmaf(yi, wq, bq);
        const float nmsx = -(qx >= 0.0f ? qx * klmx[0][c] : qx * klmn[0][c]);
        const float nmcy = -(qy >= 0.0f ? qy * klmx[0][c] : qy * klmn[0][c]);
        const float nmsy = -(qy >= 0.0f ? qy * klmx[1][c] : qy * klmn[1][c]);
        const float nmcx = -(qx >= 0.0f ? qx * klmx[1][c] : qx * klmn[1][c]);

        float s0sx = 0.f, s1sx = 0.f, s0cy = 0.f, s1cy = 0.f;
        float s0sy = 0.f, s1sy = 0.f, s0cx = 0.f, s1cx = 0.f;
        for (int j0 = 0; j0 < B_SEQ; j0 += 8) {
            float2 kx[8], ky[8];
            #pragma unroll
            for (int jj = 0; jj < 8; ++jj) kx[jj] = px[j0 + jj];  // -> ds_read_b128 x4
            #pragma unroll
            for (int jj = 0; jj < 8; ++jj) ky[jj] = py[j0 + jj];
            #pragma unroll
            for (int jj = 0; jj < 8; ++jj) {
                const float e1 = __builtin_amdgcn_exp2f(fmaf(qx, kx[jj].x, nmsx));
                const float e2 = __builtin_amdgcn_exp2f(fmaf(qy, kx[jj].x, nmcy));
                const float e3 = __builtin_amdgcn_exp2f(fmaf(qy, ky[jj].x, nmsy));
                const float e4 = __builtin_amdgcn_exp2f(fmaf(qx, ky[jj].x, nmcx));
                s1sx = fmaf(e1, kx[jj].y, s1sx); s0sx += e1;
                s1cy = fmaf(e2, kx[jj].y, s1cy); s0cy += e2;
                s1sy = fmaf(e3, ky[jj].y, s1sy); s0sy += e3;
                s1cx = fmaf(e4, ky[jj].y, s1cx); s0cx += e4;
            }
        }
        const float mx_attn = s1sx * __builtin_amdgcn_rcpf(s0sx)
                            + s1cx * __builtin_amdgcn_rcpf(s0cx);
        const float my_attn = s1sy * __builtin_amdgcn_rcpf(s0sy)
                            + s1cy * __builtin_amdgcn_rcpf(s0cy);
        out[(size_t)i * (2 * N_COL) + n0 + c]         = fmaf(alpha, mx_attn, beta2 + xi);
        out[(size_t)i * (2 * N_COL) + N_COL + n0 + c] = fmaf(alpha, my_attn, beta2 + yi);
    }
}

extern "C" void kernel_launch(void* const* d_in, const int* in_sizes, int n_in,
                              void* d_out, int out_size, void* d_ws, size_t ws_size,
                              hipStream_t stream) {
    const float* x   = (const float*)d_in[0];
    const float* y   = (const float*)d_in[1];
    const float* pwq = (const float*)d_in[2];
    const float* pwk = (const float*)d_in[3];
    const float* pwv = (const float*)d_in[4];
    const float* pbq = (const float*)d_in[5];
    const float* pbk = (const float*)d_in[6];
    const float* pbv = (const float*)d_in[7];
    const float* pwo = (const float*)d_in[8];
    const float* pbo = (const float*)d_in[9];
    float* xp  = (float*)d_ws;                 // 128*8192*4 = 4 MB scratch
    float* out = (float*)d_out;

    rsca_pool<<<dim3(2048), dim3(NT), 0, stream>>>(x, xp);
    rsca_attn<<<dim3(N_COL / TC), dim3(NT), 0, stream>>>(
        xp, y, pwq, pwk, pwv, pbq, pbk, pbv, pwo, pbo, out);
}

// Round 3
// 333.123 us; speedup vs baseline: 1.1441x; 1.1332x over previous
//
#include <hip/hip_runtime.h>

// RSCA fully-fused: AdaptiveAvgPool(7x7) + 4x scalar-embed MHA over B=128 axis
// + residuals, one kernel. x:[128,8192,7,7] f32, y:[128,8192].
//
// Math: per column n, out_attn = wo*(wv*X̄+bv)+bo where X̄ is the
// softmax(q_i*k_j)-weighted mean of RAW kv values (Σ_j a_ij = 1 folds v's
// affine into the epilogue). k stored pre-scaled by log2e in LDS ->
// inner loop per attention = fma(arg) + v_exp2 + fma(S1) + add(S0).
//
// Pooling: per 4-lane quad, one 784B row-segment (4 cols x 49 floats,
// 16B-aligned because n0%4==0). 13 interleaved float4 loads = one 64B line
// per quad per instr (fully coalesced); 3 straddling float4s fixed with
// branch-free cndmask corrections; quad shfl_xor butterfly reduce.
// LDS total 8.7 KB -> occupancy bound only by VGPRs (launch_bounds 256,4).

constexpr int B_SEQ = 128;
constexpr int N_COL = 8192;
constexpr int HWP   = 49;
constexpr int NT    = 256;
constexpr int TC    = 4;     // columns per block

__global__ __launch_bounds__(NT, 4) void rsca_fused(
    const float* __restrict__ x, const float* __restrict__ y,
    const float* __restrict__ pwq, const float* __restrict__ pwk,
    const float* __restrict__ pwv, const float* __restrict__ pbq,
    const float* __restrict__ pbk, const float* __restrict__ pbv,
    const float* __restrict__ pwo, const float* __restrict__ pbo,
    float* __restrict__ out)
{
    __shared__ float2 kvxT[TC][B_SEQ];             // [c][j] {Kl, raw}, j contiguous
    __shared__ float2 kvyT[TC][B_SEQ];
    __shared__ float  pmn[2][TC][8], pmx[2][TC][8];
    __shared__ float  klmn[2][TC], klmx[2][TC];

    const int t  = threadIdx.x;
    const int n0 = blockIdx.x * TC;

    const float wq = pwq[0], wk = pwk[0], wv = pwv[0];
    const float bq = pbq[0], bk = pbk[0], bv = pbv[0];
    const float wo = pwo[0], bo = pbo[0];
    const float L2E = 1.4426950408889634f;
    const float wkL = wk * L2E, bkL = bk * L2E;
    const float alpha = wo * wv;
    const float beta2 = 2.0f * (wo * bv + bo);

    // ---- stage y -> kvyT (coalesced-ish, 4 KB total) ----
    for (int cell = t; cell < B_SEQ * TC; cell += NT) {
        const int j = cell >> 2, c = cell & 3;
        const float fy = y[(size_t)j * N_COL + n0 + c];
        kvyT[c][j] = make_float2(fmaf(fy, wkL, bkL), fy);
    }

    // ---- pool x -> kvxT, register-direct ----
    const int ql  = t & 3;                         // lane within quad = column c
    const int seg = t >> 2;                        // 0..63 -> row j (two passes)
    for (int pass = 0; pass < 2; ++pass) {
        const int j = pass * 64 + seg;
        const float4* __restrict__ base =
            (const float4*)(x + ((size_t)j * N_COL + n0) * (size_t)HWP);
        float s0 = 0.f, s1 = 0.f, s2 = 0.f, s3 = 0.f;
        float4 v;
        // clean lines: cell = 16k/49 uniform across quad
        v = base[ql +  0]; s0 += v.x + v.y + v.z + v.w;
        v = base[ql +  4]; s0 += v.x + v.y + v.z + v.w;
        v = base[ql +  8]; s0 += v.x + v.y + v.z + v.w;
        v = base[ql + 16]; s1 += v.x + v.y + v.z + v.w;
        v = base[ql + 20]; s1 += v.x + v.y + v.z + v.w;
        v = base[ql + 28]; s2 += v.x + v.y + v.z + v.w;
        v = base[ql + 32]; s2 += v.x + v.y + v.z + v.w;
        v = base[ql + 40]; s3 += v.x + v.y + v.z + v.w;
        v = base[ql + 44]; s3 += v.x + v.y + v.z + v.w;
        // straddling lines, branch-free corrections (only ql==0 straddles)
        v = base[ql + 12];                          // floats 48+4ql .. 51+4ql
        { const float sm = v.x + v.y + v.z + v.w;
          const float cr = (ql == 0) ? v.x : 0.0f;              // float 48 -> c0
          s0 += cr; s1 += sm - cr; }
        v = base[ql + 24];                          // floats 96+4ql ..
        { const float sm = v.x + v.y + v.z + v.w;
          const float cr = (ql == 0) ? (v.x + v.y) : 0.0f;      // 96,97 -> c1
          s1 += cr; s2 += sm - cr; }
        v = base[ql + 36];                          // floats 144+4ql ..
        { const float sm = v.x + v.y + v.z + v.w;
          const float cr = (ql == 0) ? (v.x + v.y + v.z) : 0.0f; // 144..146 -> c2
          s2 += cr; s3 += sm - cr; }
        // tail m=48 (floats 192..195, cell 3): all lanes load same line,
        // added exactly once after the butterfly by the c3 owner.
        v = base[48];
        const float tail = v.x + v.y + v.z + v.w;
        // quad butterfly: every lane ends with all four cell totals
        s0 += __shfl_xor(s0, 1); s1 += __shfl_xor(s1, 1);
        s2 += __shfl_xor(s2, 1); s3 += __shfl_xor(s3, 1);
        s0 += __shfl_xor(s0, 2); s1 += __shfl_xor(s1, 2);
        s2 += __shfl_xor(s2, 2); s3 += __shfl_xor(s3, 2);
        float r = s0;
        r = (ql == 1) ? s1 : r;
        r = (ql == 2) ? s2 : r;
        r = (ql == 3) ? (s3 + tail) : r;
        const float mean = r * (1.0f / HWP);
        kvxT[ql][j] = make_float2(fmaf(mean, wkL, bkL), mean);
    }
    __syncthreads();

    // ---- per-(set,c) min/max of Kl ----
    if (t < 64) {
        const int set = t >> 5, c = (t >> 3) & 3, part = t & 7;
        float mn = 3.4e38f, mx = -3.4e38f;
        #pragma unroll
        for (int k = 0; k < 16; ++k) {
            const int j = part * 16 + k;
            const float vv = set ? kvyT[c][j].x : kvxT[c][j].x;
            mn = fminf(mn, vv);
            mx = fmaxf(mx, vv);
        }
        pmn[set][c][part] = mn;
        pmx[set][c][part] = mx;
    }
    __syncthreads();
    if (t < 8) {
        const int set = t >> 2, c = t & 3;
        float mn = 3.4e38f, mx = -3.4e38f;
        #pragma unroll
        for (int k = 0; k < 8; ++k) {
            mn = fminf(mn, pmn[set][c][k]);
            mx = fmaxf(mx, pmx[set][c][k]);
        }
        klmn[set][c] = mn;
        klmx[set][c] = mx;
    }
    __syncthreads();

    // ---- attention: thread = (query i, half ch); 2 columns each ----
    const int i  = t & (B_SEQ - 1);
    const int ch = t >> 7;
    #pragma unroll
    for (int cc = 0; cc < 2; ++cc) {
        const int c = ch * 2 + cc;                  // wave-uniform -> LDS broadcast
        const float2* __restrict__ px = kvxT[c];
        const float2* __restrict__ py = kvyT[c];
        const float xi = px[i].y;
        const float yi = py[i].y;
        const float qx = fmaf(xi, wq, bq);
        const float qy = fmaf(yi, wq, bq);
        const float nmsx = -(qx >= 0.0f ? qx * klmx[0][c] : qx * klmn[0][c]);
        const float nmcy = -(qy >= 0.0f ? qy * klmx[0][c] : qy * klmn[0][c]);
        const float nmsy = -(qy >= 0.0f ? qy * klmx[1][c] : qy * klmn[1][c]);
        const float nmcx = -(qx >= 0.0f ? qx * klmx[1][c] : qx * klmn[1][c]);

        float s0sx = 0.f, s1sx = 0.f, s0cy = 0.f, s1cy = 0.f;
        float s0sy = 0.f, s1sy = 0.f, s0cx = 0.f, s1cx = 0.f;
        for (int j0 = 0; j0 < B_SEQ; j0 += 8) {
            float2 kx[8], ky[8];
            #pragma unroll
            for (int jj = 0; jj < 8; ++jj) kx[jj] = px[j0 + jj];  // ds_read_b128 x4
            #pragma unroll
            for (int jj = 0; jj < 8; ++jj) ky[jj] = py[j0 + jj];
            #pragma unroll
            for (int jj = 0; jj < 8; ++jj) {
                const float e1 = __builtin_amdgcn_exp2f(fmaf(qx, kx[jj].x, nmsx));
                const float e2 = __builtin_amdgcn_exp2f(fmaf(qy, kx[jj].x, nmcy));
                const float e3 = __builtin_amdgcn_exp2f(fmaf(qy, ky[jj].x, nmsy));
                const float e4 = __builtin_amdgcn_exp2f(fmaf(qx, ky[jj].x, nmcx));
                s1sx = fmaf(e1, kx[jj].y, s1sx); s0sx += e1;
                s1cy = fmaf(e2, kx[jj].y, s1cy); s0cy += e2;
                s1sy = fmaf(e3, ky[jj].y, s1sy); s0sy += e3;
                s1cx = fmaf(e4, ky[jj].y, s1cx); s0cx += e4;
            }
        }
        const float mx_attn = s1sx * __builtin_amdgcn_rcpf(s0sx)
                            + s1cx * __builtin_amdgcn_rcpf(s0cx);
        const float my_attn = s1sy * __builtin_amdgcn_rcpf(s0sy)
                            + s1cy * __builtin_amdgcn_rcpf(s0cy);
        out[(size_t)i * (2 * N_COL) + n0 + c]         = fmaf(alpha, mx_attn, beta2 + xi);
        out[(size_t)i * (2 * N_COL) + N_COL + n0 + c] = fmaf(alpha, my_attn, beta2 + yi);
    }
}

extern "C" void kernel_launch(void* const* d_in, const int* in_sizes, int n_in,
                              void* d_out, int out_size, void* d_ws, size_t ws_size,
                              hipStream_t stream) {
    const float* x   = (const float*)d_in[0];
    const float* y   = (const float*)d_in[1];
    const float* pwq = (const float*)d_in[2];
    const float* pwk = (const float*)d_in[3];
    const float* pwv = (const float*)d_in[4];
    const float* pbq = (const float*)d_in[5];
    const float* pbk = (const float*)d_in[6];
    const float* pbv = (const float*)d_in[7];
    const float* pwo = (const float*)d_in[8];
    const float* pbo = (const float*)d_in[9];
    float* out = (float*)d_out;

    rsca_fused<<<dim3(N_COL / TC), dim3(NT), 0, stream>>>(
        x, y, pwq, pwk, pwv, pbq, pbk, pbv, pwo, pbo, out);
}